// Round 4
// baseline (460.986 us; speedup 1.0000x reference)
//
#include <hip/hip_runtime.h>
#include <hip/hip_fp16.h>

// Scatter-mean voxel pooling, bucketed one-atomic-pass, fused cell records.
// N=1e6 points, C=64 channels, K=64 grid (262144 cells, Poisson lambda=3.81).
//
// Round-7 change: round 3 (fp16 gather rows) crashed the container — prime
// suspect is workspace overflow: it assumed ws_size >= 145 MB (128 MB fp16
// feature mirror) without checking. This round gates the fp16 path on
// ws_size at launch: if rec+spill+n*128B fits, run the fp16 design (point
// row = 128 B = ONE random L2 line, halving reduce's scattered-line count);
// otherwise fall back to the round-2 fp32 design (17 MB, measured 419 us).
// Everything else (record layout, clamped 8-gather, spill exactness) is
// unchanged from the passing round-2 kernel.

#define KGRID  64
#define NCH    64
#define NCELLS (KGRID * KGRID * KGRID)   // 262144
#define CAP    15                        // slots per 64-B record
#define SPILLCAP 8192

typedef float f32x4 __attribute__((ext_vector_type(4)));

union HU { unsigned u; __half2 h; };

__device__ __forceinline__ int cell_of(float px, float py, float pz) {
    int ix = min(max((int)floorf((px + 1.0f) * 32.0f), 0), KGRID - 1);
    int iy = min(max((int)floorf((py + 1.0f) * 32.0f), 0), KGRID - 1);
    int iz = min(max((int)floorf((pz + 1.0f) * 32.0f), 0), KGRID - 1);
    return (ix << 12) | (iy << 6) | iz;
}

__device__ __forceinline__ void fadd4(float4& a, const float4& b) {
    a.x += b.x; a.y += b.y; a.z += b.z; a.w += b.w;
}

// Unpack one 8-B chunk (4 fp16 channels) and accumulate into fp32.
__device__ __forceinline__ void hacc(float4& a, uint2 q) {
    HU u0, u1; u0.u = q.x; u1.u = q.y;
    float2 f0 = __half22float2(u0.h);
    float2 f1 = __half22float2(u1.h);
    a.x += f0.x; a.y += f0.y; a.z += f1.x; a.w += f1.y;
}

// Part 1 (4 points/thread): cell id + slot reservation into 64-B records.
// Part 2 (grid-stride, only if do_convert): fp32 -> fp16 row conversion.
__global__ __launch_bounds__(256) void assign_pts(
    const float* __restrict__ pts,
    const f32x4* __restrict__ feat4,
    uint2* __restrict__ feat16,
    int* __restrict__ rec,
    int* __restrict__ nspill,
    int* __restrict__ spill,
    int n, int nthreads, int do_convert)
{
    int t = blockIdx.x * blockDim.x + threadIdx.x;
    int p0 = t * 4;
    if (p0 + 4 <= n) {
        const float4* p4 = (const float4*)(pts + (size_t)p0 * 3);
        float4 a = p4[0], b = p4[1], c = p4[2];
        int cid[4];
        cid[0] = cell_of(a.x, a.y, a.z);
        cid[1] = cell_of(a.w, b.x, b.y);
        cid[2] = cell_of(b.z, b.w, c.x);
        cid[3] = cell_of(c.y, c.z, c.w);
        #pragma unroll
        for (int i = 0; i < 4; ++i) {
            int* base = rec + ((size_t)cid[i] << 4);
            int slot = __hip_atomic_fetch_add(base, 1, __ATOMIC_RELAXED,
                                              __HIP_MEMORY_SCOPE_AGENT);
            if (slot < CAP) {
                base[1 + slot] = p0 + i;     // same 64-B line as the atomic
            } else {
                int s = atomicAdd(nspill, 1);
                if (s < SPILLCAP) { spill[2 * s] = cid[i]; spill[2 * s + 1] = p0 + i; }
            }
        }
    } else if (p0 < n) {
        for (int p = p0; p < n; ++p) {
            int c = cell_of(pts[3 * p], pts[3 * p + 1], pts[3 * p + 2]);
            int* base = rec + ((size_t)c << 4);
            int slot = __hip_atomic_fetch_add(base, 1, __ATOMIC_RELAXED,
                                              __HIP_MEMORY_SCOPE_AGENT);
            if (slot < CAP) {
                base[1 + slot] = p;
            } else {
                int s = atomicAdd(nspill, 1);
                if (s < SPILLCAP) { spill[2 * s] = c; spill[2 * s + 1] = p; }
            }
        }
    }

    if (do_convert) {
        // fp32 -> fp16 streaming convert: chunk = 4 ch (16 B in, 8 B out).
        int total = n * (NCH / 4);
        for (int idx = t; idx < total; idx += nthreads) {
            f32x4 v = __builtin_nontemporal_load(feat4 + idx);
            HU u0, u1;
            u0.h = __floats2half2_rn(v.x, v.y);
            u1.h = __floats2half2_rn(v.z, v.w);
            uint2 q; q.x = u0.u; q.y = u1.u;
            feat16[idx] = q;             // cached: reduce re-reads via L3
        }
    }
}

// fp16 reducer: one wave = 4 cells; ch4 = lane&15 reads one 8-B chunk of each
// point row -> 16 lanes x 8 B = 128 B = ONE L2 line per point row.
__global__ __launch_bounds__(256) void reduce_bucket16(
    const uint2* __restrict__ feat16,
    const int* __restrict__ rec,
    const int* __restrict__ nspill,
    const int* __restrict__ spill,
    f32x4* __restrict__ out4)
{
    int lane = threadIdx.x & 63;
    int wave = (int)((blockIdx.x * blockDim.x + threadIdx.x) >> 6);
    int grp  = lane >> 4;
    int ch4  = lane & 15;
    int cell = wave * 4 + grp;

    const int4* r4 = (const int4*)(rec + ((size_t)cell << 4));
    int4 r0 = r4[0];
    int4 r1 = r4[1];
    int4 r2 = r4[2];
    int4 r3 = r4[3];

    int cnt = r0.x;
    int len = min(cnt, CAP);
    int e0 = (len > 0) ? r0.y : 0;
    int e1 = (len > 1) ? r0.z : e0;
    int e2 = (len > 2) ? r0.w : e0;
    int e3 = (len > 3) ? r1.x : e0;
    int e4 = (len > 4) ? r1.y : e0;
    int e5 = (len > 5) ? r1.z : e0;
    int e6 = (len > 6) ? r1.w : e0;
    int e7 = (len > 7) ? r2.x : e0;

    const uint2* fb = feat16 + ch4;     // row stride = 16 chunks (128 B)
    uint2 q0 = fb[(size_t)e0 * 16];
    uint2 q1 = fb[(size_t)e1 * 16];
    uint2 q2 = fb[(size_t)e2 * 16];
    uint2 q3 = fb[(size_t)e3 * 16];
    uint2 q4 = fb[(size_t)e4 * 16];
    uint2 q5 = fb[(size_t)e5 * 16];
    uint2 q6 = fb[(size_t)e6 * 16];
    uint2 q7 = fb[(size_t)e7 * 16];

    float4 acc = make_float4(0.f, 0.f, 0.f, 0.f);
    if (len > 0) hacc(acc, q0);
    if (len > 1) hacc(acc, q1);
    if (len > 2) hacc(acc, q2);
    if (len > 3) hacc(acc, q3);
    if (len > 4) hacc(acc, q4);
    if (len > 5) hacc(acc, q5);
    if (len > 6) hacc(acc, q6);
    if (len > 7) hacc(acc, q7);

    if (len > 8) {
        hacc(acc, fb[(size_t)r2.y * 16]);
        if (len > 9)  hacc(acc, fb[(size_t)r2.z * 16]);
        if (len > 10) hacc(acc, fb[(size_t)r2.w * 16]);
        if (len > 11) hacc(acc, fb[(size_t)r3.x * 16]);
        if (len > 12) hacc(acc, fb[(size_t)r3.y * 16]);
        if (len > 13) hacc(acc, fb[(size_t)r3.z * 16]);
        if (len > 14) hacc(acc, fb[(size_t)r3.w * 16]);
    }
    if (cnt > CAP) {
        int ns = min(*nspill, SPILLCAP);
        for (int s = 0; s < ns; ++s) {
            if (spill[2 * s] == cell) hacc(acc, fb[(size_t)spill[2 * s + 1] * 16]);
        }
    }
    float inv = 1.0f / (float)max(cnt, 1);
    f32x4 o;
    o.x = acc.x * inv; o.y = acc.y * inv; o.z = acc.z * inv; o.w = acc.w * inv;
    __builtin_nontemporal_store(o, out4 + (size_t)wave * 64 + lane);
}

// fp32 fallback reducer (round-2 design, measured 419 us total): gathers
// 256-B rows straight from the input features. Used when ws can't hold feat16.
__global__ __launch_bounds__(256) void reduce_bucket32(
    const float4* __restrict__ feat4,
    const int* __restrict__ rec,
    const int* __restrict__ nspill,
    const int* __restrict__ spill,
    float4* __restrict__ out4)
{
    int lane = threadIdx.x & 63;
    int wave = (int)((blockIdx.x * blockDim.x + threadIdx.x) >> 6);
    int grp  = lane >> 4;
    int ch4  = lane & 15;
    int cell = wave * 4 + grp;

    const int4* r4 = (const int4*)(rec + ((size_t)cell << 4));
    int4 r0 = r4[0];
    int4 r1 = r4[1];
    int4 r2 = r4[2];
    int4 r3 = r4[3];

    int cnt = r0.x;
    int len = min(cnt, CAP);
    int e0 = (len > 0) ? r0.y : 0;
    int e1 = (len > 1) ? r0.z : e0;
    int e2 = (len > 2) ? r0.w : e0;
    int e3 = (len > 3) ? r1.x : e0;
    int e4 = (len > 4) ? r1.y : e0;
    int e5 = (len > 5) ? r1.z : e0;
    int e6 = (len > 6) ? r1.w : e0;
    int e7 = (len > 7) ? r2.x : e0;

    const float4* fb = feat4 + ch4;
    float4 f0 = fb[(size_t)e0 * 16];
    float4 f1 = fb[(size_t)e1 * 16];
    float4 f2 = fb[(size_t)e2 * 16];
    float4 f3 = fb[(size_t)e3 * 16];
    float4 f4 = fb[(size_t)e4 * 16];
    float4 f5 = fb[(size_t)e5 * 16];
    float4 f6 = fb[(size_t)e6 * 16];
    float4 f7 = fb[(size_t)e7 * 16];

    float4 acc = make_float4(0.f, 0.f, 0.f, 0.f);
    if (len > 0) fadd4(acc, f0);
    if (len > 1) fadd4(acc, f1);
    if (len > 2) fadd4(acc, f2);
    if (len > 3) fadd4(acc, f3);
    if (len > 4) fadd4(acc, f4);
    if (len > 5) fadd4(acc, f5);
    if (len > 6) fadd4(acc, f6);
    if (len > 7) fadd4(acc, f7);

    if (len > 8) {
        fadd4(acc, fb[(size_t)r2.y * 16]);
        if (len > 9)  fadd4(acc, fb[(size_t)r2.z * 16]);
        if (len > 10) fadd4(acc, fb[(size_t)r2.w * 16]);
        if (len > 11) fadd4(acc, fb[(size_t)r3.x * 16]);
        if (len > 12) fadd4(acc, fb[(size_t)r3.y * 16]);
        if (len > 13) fadd4(acc, fb[(size_t)r3.z * 16]);
        if (len > 14) fadd4(acc, fb[(size_t)r3.w * 16]);
    }
    if (cnt > CAP) {
        int ns = min(*nspill, SPILLCAP);
        for (int s = 0; s < ns; ++s) {
            if (spill[2 * s] == cell) fadd4(acc, fb[(size_t)spill[2 * s + 1] * 16]);
        }
    }
    float inv = 1.0f / (float)max(cnt, 1);
    acc.x *= inv; acc.y *= inv; acc.z *= inv; acc.w *= inv;
    out4[(size_t)wave * 64 + lane] = acc;
}

extern "C" void kernel_launch(void* const* d_in, const int* in_sizes, int n_in,
                              void* d_out, int out_size, void* d_ws, size_t ws_size,
                              hipStream_t stream)
{
    const float* feat = (const float*)d_in[0];   // (N, 64) fp32
    const float* pts  = (const float*)d_in[1];   // (N, 3)  fp32
    float* out = (float*)d_out;                  // (64,64,64,64) fp32

    const int n = in_sizes[0] / NCH;

    // Workspace: rec (NCELLS*16 ints) | nspill (1,+3) | spill (2*SPILLCAP)
    //            | feat16 (n*16 uint2 = n*128 B)  [only if ws_size permits]
    int* rec    = (int*)d_ws;                    // 16 MB of 64-B records
    int* nspill = rec + (size_t)NCELLS * 16;     // 1 (+3 pad)
    int* spill  = nspill + 4;                    // 2*SPILLCAP
    uint2* feat16 = (uint2*)(spill + 2 * SPILLCAP);  // 8-B aligned

    size_t base_bytes = ((size_t)NCELLS * 16 + 4 + 2 * SPILLCAP) * sizeof(int);
    size_t need16     = base_bytes + (size_t)n * 128;
    int use16 = (ws_size >= need16) ? 1 : 0;

    hipMemsetAsync(rec, 0, ((size_t)NCELLS * 16 + 4) * sizeof(int), stream);

    int t4 = (n + 3) / 4;
    int pblocks = (t4 + 255) / 256;
    int nthreads = pblocks * 256;
    assign_pts<<<pblocks, 256, 0, stream>>>(
        pts, (const f32x4*)feat, feat16, rec, nspill, spill, n, nthreads, use16);

    if (use16) {
        reduce_bucket16<<<NCELLS / 16, 256, 0, stream>>>(
            (const uint2*)feat16, rec, nspill, spill, (f32x4*)out);
    } else {
        reduce_bucket32<<<NCELLS / 16, 256, 0, stream>>>(
            (const float4*)feat, rec, nspill, spill, (float4*)out);
    }
}

// Round 6
// 425.680 us; speedup vs baseline: 1.0829x; 1.0829x over previous
//
#include <hip/hip_runtime.h>

// Scatter-mean voxel pooling, bucketed one-atomic-pass, fused cell records.
// N=1e6 points, C=64 channels, K=64 grid (262144 cells, Poisson lambda=3.81).
//
// Round-9: identical design to round-8 (8 cells/wave, 16 clamped gathers in
// flight, fp32 rows from input feat, NT out stores) with the compile error
// fixed: output pointer type unified to f32x4* end-to-end (round 8 declared
// float4* in the kernel but cast f32x4* at launch).

#define KGRID  64
#define NCH    64
#define NCELLS (KGRID * KGRID * KGRID)   // 262144
#define CAP    15                        // slots per 64-B record
#define SPILLCAP 8192

typedef float f32x4 __attribute__((ext_vector_type(4)));

__device__ __forceinline__ int cell_of(float px, float py, float pz) {
    int ix = min(max((int)floorf((px + 1.0f) * 32.0f), 0), KGRID - 1);
    int iy = min(max((int)floorf((py + 1.0f) * 32.0f), 0), KGRID - 1);
    int iz = min(max((int)floorf((pz + 1.0f) * 32.0f), 0), KGRID - 1);
    return (ix << 12) | (iy << 6) | iz;
}

__device__ __forceinline__ void fadd4(float4& a, const float4& b) {
    a.x += b.x; a.y += b.y; a.z += b.z; a.w += b.w;
}

// 4 points per thread: 3 float4 loads = 12 floats = 4 points. One atomic
// slot-reserve + one same-line slot store per point (64-B cell records).
__global__ __launch_bounds__(256) void assign_pts(
    const float* __restrict__ pts,
    int* __restrict__ rec,
    int* __restrict__ nspill,
    int* __restrict__ spill,
    int n)
{
    int t = blockIdx.x * blockDim.x + threadIdx.x;
    int p0 = t * 4;
    if (p0 >= n) return;
    if (p0 + 4 <= n) {
        const float4* p4 = (const float4*)(pts + (size_t)p0 * 3);
        float4 a = p4[0], b = p4[1], c = p4[2];
        int cid[4];
        cid[0] = cell_of(a.x, a.y, a.z);
        cid[1] = cell_of(a.w, b.x, b.y);
        cid[2] = cell_of(b.z, b.w, c.x);
        cid[3] = cell_of(c.y, c.z, c.w);
        #pragma unroll
        for (int i = 0; i < 4; ++i) {
            int* base = rec + ((size_t)cid[i] << 4);
            int slot = __hip_atomic_fetch_add(base, 1, __ATOMIC_RELAXED,
                                              __HIP_MEMORY_SCOPE_AGENT);
            if (slot < CAP) {
                base[1 + slot] = p0 + i;     // same 64-B line as the atomic
            } else {
                int s = atomicAdd(nspill, 1);
                if (s < SPILLCAP) { spill[2 * s] = cid[i]; spill[2 * s + 1] = p0 + i; }
            }
        }
    } else {
        for (int p = p0; p < n; ++p) {
            int c = cell_of(pts[3 * p], pts[3 * p + 1], pts[3 * p + 2]);
            int* base = rec + ((size_t)c << 4);
            int slot = __hip_atomic_fetch_add(base, 1, __ATOMIC_RELAXED,
                                              __HIP_MEMORY_SCOPE_AGENT);
            if (slot < CAP) {
                base[1 + slot] = p;
            } else {
                int s = atomicAdd(nspill, 1);
                if (s < SPILLCAP) { spill[2 * s] = c; spill[2 * s + 1] = p; }
            }
        }
    }
}

// One wave = 8 cells (two 4-cell record sets A,B). grp = lane>>4 owns cells
// {wave*8+grp, wave*8+4+grp}; ch4 = lane&15 spans each 64-ch row as float4s.
// All 8 record loads then all 16 clamped row-gathers issue before any
// accumulation -> ~16 scattered requests in flight per wave (2x round-2).
// Tail slots 8..14 come from record registers (rare); spill list for cnt>15.
__global__ __launch_bounds__(256) void reduce_bucket(
    const float4* __restrict__ feat4,
    const int* __restrict__ rec,
    const int* __restrict__ nspill,
    const int* __restrict__ spill,
    f32x4* __restrict__ out4)
{
    int lane = threadIdx.x & 63;
    int wave = (int)((blockIdx.x * blockDim.x + threadIdx.x) >> 6);
    int grp  = lane >> 4;
    int ch4  = lane & 15;
    int cellA = wave * 8 + grp;          // grid sized exactly: cellB < NCELLS
    int cellB = cellA + 4;

    const int4* rA = (const int4*)(rec + ((size_t)cellA << 4));
    const int4* rB = (const int4*)(rec + ((size_t)cellB << 4));
    int4 a0 = rA[0], a1 = rA[1], a2 = rA[2], a3 = rA[3];
    int4 b0 = rB[0], b1 = rB[1], b2 = rB[2], b3 = rB[3];

    int cntA = a0.x, lenA = min(cntA, CAP);
    int cntB = b0.x, lenB = min(cntB, CAP);

    int eA0 = (lenA > 0) ? a0.y : 0;     // empty cell -> harmless row 0 read
    int eA1 = (lenA > 1) ? a0.z : eA0;
    int eA2 = (lenA > 2) ? a0.w : eA0;
    int eA3 = (lenA > 3) ? a1.x : eA0;
    int eA4 = (lenA > 4) ? a1.y : eA0;
    int eA5 = (lenA > 5) ? a1.z : eA0;
    int eA6 = (lenA > 6) ? a1.w : eA0;
    int eA7 = (lenA > 7) ? a2.x : eA0;
    int eB0 = (lenB > 0) ? b0.y : 0;
    int eB1 = (lenB > 1) ? b0.z : eB0;
    int eB2 = (lenB > 2) ? b0.w : eB0;
    int eB3 = (lenB > 3) ? b1.x : eB0;
    int eB4 = (lenB > 4) ? b1.y : eB0;
    int eB5 = (lenB > 5) ? b1.z : eB0;
    int eB6 = (lenB > 6) ? b1.w : eB0;
    int eB7 = (lenB > 7) ? b2.x : eB0;

    const float4* fb = feat4 + ch4;
    float4 fA0 = fb[(size_t)eA0 * 16];
    float4 fA1 = fb[(size_t)eA1 * 16];
    float4 fA2 = fb[(size_t)eA2 * 16];
    float4 fA3 = fb[(size_t)eA3 * 16];
    float4 fA4 = fb[(size_t)eA4 * 16];
    float4 fA5 = fb[(size_t)eA5 * 16];
    float4 fA6 = fb[(size_t)eA6 * 16];
    float4 fA7 = fb[(size_t)eA7 * 16];
    float4 fB0 = fb[(size_t)eB0 * 16];
    float4 fB1 = fb[(size_t)eB1 * 16];
    float4 fB2 = fb[(size_t)eB2 * 16];
    float4 fB3 = fb[(size_t)eB3 * 16];
    float4 fB4 = fb[(size_t)eB4 * 16];
    float4 fB5 = fb[(size_t)eB5 * 16];
    float4 fB6 = fb[(size_t)eB6 * 16];
    float4 fB7 = fb[(size_t)eB7 * 16];

    float4 accA = make_float4(0.f, 0.f, 0.f, 0.f);
    if (lenA > 0) fadd4(accA, fA0);
    if (lenA > 1) fadd4(accA, fA1);
    if (lenA > 2) fadd4(accA, fA2);
    if (lenA > 3) fadd4(accA, fA3);
    if (lenA > 4) fadd4(accA, fA4);
    if (lenA > 5) fadd4(accA, fA5);
    if (lenA > 6) fadd4(accA, fA6);
    if (lenA > 7) fadd4(accA, fA7);

    float4 accB = make_float4(0.f, 0.f, 0.f, 0.f);
    if (lenB > 0) fadd4(accB, fB0);
    if (lenB > 1) fadd4(accB, fB1);
    if (lenB > 2) fadd4(accB, fB2);
    if (lenB > 3) fadd4(accB, fB3);
    if (lenB > 4) fadd4(accB, fB4);
    if (lenB > 5) fadd4(accB, fB5);
    if (lenB > 6) fadd4(accB, fB6);
    if (lenB > 7) fadd4(accB, fB7);

    if (lenA > 8) {                      // ~1.5% of cells; slots from registers
        fadd4(accA, fb[(size_t)a2.y * 16]);
        if (lenA > 9)  fadd4(accA, fb[(size_t)a2.z * 16]);
        if (lenA > 10) fadd4(accA, fb[(size_t)a2.w * 16]);
        if (lenA > 11) fadd4(accA, fb[(size_t)a3.x * 16]);
        if (lenA > 12) fadd4(accA, fb[(size_t)a3.y * 16]);
        if (lenA > 13) fadd4(accA, fb[(size_t)a3.z * 16]);
        if (lenA > 14) fadd4(accA, fb[(size_t)a3.w * 16]);
    }
    if (lenB > 8) {
        fadd4(accB, fb[(size_t)b2.y * 16]);
        if (lenB > 9)  fadd4(accB, fb[(size_t)b2.z * 16]);
        if (lenB > 10) fadd4(accB, fb[(size_t)b2.w * 16]);
        if (lenB > 11) fadd4(accB, fb[(size_t)b3.x * 16]);
        if (lenB > 12) fadd4(accB, fb[(size_t)b3.y * 16]);
        if (lenB > 13) fadd4(accB, fb[(size_t)b3.z * 16]);
        if (lenB > 14) fadd4(accB, fb[(size_t)b3.w * 16]);
    }
    if (cntA > CAP) {                    // ~0.4 cells per grid; exactness guard
        int ns = min(*nspill, SPILLCAP);
        for (int s = 0; s < ns; ++s) {
            if (spill[2 * s] == cellA) fadd4(accA, fb[(size_t)spill[2 * s + 1] * 16]);
        }
    }
    if (cntB > CAP) {
        int ns = min(*nspill, SPILLCAP);
        for (int s = 0; s < ns; ++s) {
            if (spill[2 * s] == cellB) fadd4(accB, fb[(size_t)spill[2 * s + 1] * 16]);
        }
    }

    float invA = 1.0f / (float)max(cntA, 1);
    float invB = 1.0f / (float)max(cntB, 1);
    f32x4 oA, oB;
    oA.x = accA.x * invA; oA.y = accA.y * invA;
    oA.z = accA.z * invA; oA.w = accA.w * invA;
    oB.x = accB.x * invB; oB.y = accB.y * invB;
    oB.z = accB.z * invB; oB.w = accB.w * invB;

    // NT stores: out never re-read; keep L3 capacity for feat rows.
    f32x4* ob = out4 + (size_t)wave * 128;
    __builtin_nontemporal_store(oA, ob + lane);        // cells A: wave*8+0..3
    __builtin_nontemporal_store(oB, ob + 64 + lane);   // cells B: wave*8+4..7
}

extern "C" void kernel_launch(void* const* d_in, const int* in_sizes, int n_in,
                              void* d_out, int out_size, void* d_ws, size_t ws_size,
                              hipStream_t stream)
{
    const float* feat = (const float*)d_in[0];   // (N, 64) fp32
    const float* pts  = (const float*)d_in[1];   // (N, 3)  fp32
    float* out = (float*)d_out;                  // (64,64,64,64) fp32

    const int n = in_sizes[0] / NCH;

    // Workspace (ints): rec (NCELLS*16) | nspill (1,+3 pad) | spill (2*SPILLCAP)
    // Total: 4194304 + 4 + 16384 ints = ~16.8 MB (same as passing round-2).
    int* rec    = (int*)d_ws;                    // NCELLS * 16, 64-B records
    int* nspill = rec + (size_t)NCELLS * 16;     // 1 (+3 pad)
    int* spill  = nspill + 4;                    // 2*SPILLCAP

    (void)hipMemsetAsync(rec, 0, ((size_t)NCELLS * 16 + 4) * sizeof(int), stream);

    int t4 = (n + 3) / 4;
    int pblocks = (t4 + 255) / 256;
    assign_pts<<<pblocks, 256, 0, stream>>>(pts, rec, nspill, spill, n);

    // 32768 waves (8 cells each) = 8192 blocks of 4 waves.
    reduce_bucket<<<NCELLS / 32, 256, 0, stream>>>(
        (const float4*)feat, rec, nspill, spill, (f32x4*)out);
}

// Round 7
// 421.222 us; speedup vs baseline: 1.0944x; 1.0106x over previous
//
#include <hip/hip_runtime.h>

// Scatter-mean voxel pooling, bucketed one-atomic-pass, fused cell records.
// N=1e6 points, C=64 channels, K=64 grid (262144 cells, Poisson lambda=3.81).
//
// Round-10: reduce reverted to the measured-best round-2 form (4 cells/wave,
// 8 clamped gathers, plain stores) — round-6's 8-cell+NT variant was +6us.
// assign now processes 8 points/thread = 8 INDEPENDENT atomic->store chains
// (was 4), testing whether assign is atomic-latency-chain bound (predict
// -15..25us) or at the same scattered-request service wall as reduce
// (predict flat -> structural floor reached for scatter decompositions).

#define KGRID  64
#define NCH    64
#define NCELLS (KGRID * KGRID * KGRID)   // 262144
#define CAP    15                        // slots per 64-B record
#define SPILLCAP 8192

__device__ __forceinline__ int cell_of(float px, float py, float pz) {
    int ix = min(max((int)floorf((px + 1.0f) * 32.0f), 0), KGRID - 1);
    int iy = min(max((int)floorf((py + 1.0f) * 32.0f), 0), KGRID - 1);
    int iz = min(max((int)floorf((pz + 1.0f) * 32.0f), 0), KGRID - 1);
    return (ix << 12) | (iy << 6) | iz;
}

__device__ __forceinline__ void fadd4(float4& a, const float4& b) {
    a.x += b.x; a.y += b.y; a.z += b.z; a.w += b.w;
}

// 8 points per thread: 6 float4 loads = 24 floats = 8 points. One atomic
// slot-reserve + one same-line dependent store per point; the 8 chains are
// mutually independent -> 8 atomic round-trips in flight per thread.
__global__ __launch_bounds__(256) void assign_pts(
    const float* __restrict__ pts,
    int* __restrict__ rec,
    int* __restrict__ nspill,
    int* __restrict__ spill,
    int n)
{
    int t = blockIdx.x * blockDim.x + threadIdx.x;
    int p0 = t * 8;
    if (p0 >= n) return;
    if (p0 + 8 <= n) {
        const float4* p4 = (const float4*)(pts + (size_t)p0 * 3);
        float4 a = p4[0], b = p4[1], c = p4[2];
        float4 d = p4[3], e = p4[4], f = p4[5];
        int cid[8];
        cid[0] = cell_of(a.x, a.y, a.z);
        cid[1] = cell_of(a.w, b.x, b.y);
        cid[2] = cell_of(b.z, b.w, c.x);
        cid[3] = cell_of(c.y, c.z, c.w);
        cid[4] = cell_of(d.x, d.y, d.z);
        cid[5] = cell_of(d.w, e.x, e.y);
        cid[6] = cell_of(e.z, e.w, f.x);
        cid[7] = cell_of(f.y, f.z, f.w);
        #pragma unroll
        for (int i = 0; i < 8; ++i) {
            int* base = rec + ((size_t)cid[i] << 4);
            int slot = __hip_atomic_fetch_add(base, 1, __ATOMIC_RELAXED,
                                              __HIP_MEMORY_SCOPE_AGENT);
            if (slot < CAP) {
                base[1 + slot] = p0 + i;     // same 64-B line as the atomic
            } else {
                int s = atomicAdd(nspill, 1);
                if (s < SPILLCAP) { spill[2 * s] = cid[i]; spill[2 * s + 1] = p0 + i; }
            }
        }
    } else {
        for (int p = p0; p < n; ++p) {
            int c = cell_of(pts[3 * p], pts[3 * p + 1], pts[3 * p + 2]);
            int* base = rec + ((size_t)c << 4);
            int slot = __hip_atomic_fetch_add(base, 1, __ATOMIC_RELAXED,
                                              __HIP_MEMORY_SCOPE_AGENT);
            if (slot < CAP) {
                base[1 + slot] = p;
            } else {
                int s = atomicAdd(nspill, 1);
                if (s < SPILLCAP) { spill[2 * s] = c; spill[2 * s + 1] = p; }
            }
        }
    }
}

// One wave = 4 cells (round-2 measured-best form). grp = lane>>4 owns cell
// wave*4+grp; ch4 = lane&15 spans the 64-ch row as float4s. One 64-B record
// load (4x int4 issued together) delivers count + 15 slots; first 8 point
// rows fetched with clamped indices (dups are L1 hits) -> 8 independent
// gathers in flight. Slots 8..14 from record registers; spill for cnt>15.
__global__ __launch_bounds__(256) void reduce_bucket(
    const float4* __restrict__ feat4,
    const int* __restrict__ rec,
    const int* __restrict__ nspill,
    const int* __restrict__ spill,
    float4* __restrict__ out4)
{
    int lane = threadIdx.x & 63;
    int wave = (int)((blockIdx.x * blockDim.x + threadIdx.x) >> 6);
    int grp  = lane >> 4;
    int ch4  = lane & 15;
    int cell = wave * 4 + grp;          // grid sized exactly: cell < NCELLS

    const int4* r4 = (const int4*)(rec + ((size_t)cell << 4));
    int4 r0 = r4[0];                    // {cnt, s0, s1, s2}
    int4 r1 = r4[1];                    // {s3, s4, s5, s6}
    int4 r2 = r4[2];                    // {s7, s8, s9, s10}
    int4 r3 = r4[3];                    // {s11, s12, s13, s14}

    int cnt = r0.x;
    int len = min(cnt, CAP);
    int e0 = (len > 0) ? r0.y : 0;      // empty cell -> harmless row 0 read
    int e1 = (len > 1) ? r0.z : e0;
    int e2 = (len > 2) ? r0.w : e0;
    int e3 = (len > 3) ? r1.x : e0;
    int e4 = (len > 4) ? r1.y : e0;
    int e5 = (len > 5) ? r1.z : e0;
    int e6 = (len > 6) ? r1.w : e0;
    int e7 = (len > 7) ? r2.x : e0;

    const float4* fb = feat4 + ch4;
    float4 f0 = fb[(size_t)e0 * 16];
    float4 f1 = fb[(size_t)e1 * 16];
    float4 f2 = fb[(size_t)e2 * 16];
    float4 f3 = fb[(size_t)e3 * 16];
    float4 f4 = fb[(size_t)e4 * 16];
    float4 f5 = fb[(size_t)e5 * 16];
    float4 f6 = fb[(size_t)e6 * 16];
    float4 f7 = fb[(size_t)e7 * 16];

    float4 acc = make_float4(0.f, 0.f, 0.f, 0.f);
    if (len > 0) fadd4(acc, f0);
    if (len > 1) fadd4(acc, f1);
    if (len > 2) fadd4(acc, f2);
    if (len > 3) fadd4(acc, f3);
    if (len > 4) fadd4(acc, f4);
    if (len > 5) fadd4(acc, f5);
    if (len > 6) fadd4(acc, f6);
    if (len > 7) fadd4(acc, f7);

    if (len > 8) {                      // ~1.5% of cells; slots from registers
        fadd4(acc, fb[(size_t)r2.y * 16]);
        if (len > 9)  fadd4(acc, fb[(size_t)r2.z * 16]);
        if (len > 10) fadd4(acc, fb[(size_t)r2.w * 16]);
        if (len > 11) fadd4(acc, fb[(size_t)r3.x * 16]);
        if (len > 12) fadd4(acc, fb[(size_t)r3.y * 16]);
        if (len > 13) fadd4(acc, fb[(size_t)r3.z * 16]);
        if (len > 14) fadd4(acc, fb[(size_t)r3.w * 16]);
    }
    if (cnt > CAP) {                    // ~0.4 cells per grid; exactness guard
        int ns = min(*nspill, SPILLCAP);
        for (int s = 0; s < ns; ++s) {
            if (spill[2 * s] == cell) fadd4(acc, fb[(size_t)spill[2 * s + 1] * 16]);
        }
    }
    float inv = 1.0f / (float)max(cnt, 1);
    acc.x *= inv; acc.y *= inv; acc.z *= inv; acc.w *= inv;

    out4[(size_t)wave * 64 + lane] = acc;   // == out4[cell*16 + ch4], contiguous
}

extern "C" void kernel_launch(void* const* d_in, const int* in_sizes, int n_in,
                              void* d_out, int out_size, void* d_ws, size_t ws_size,
                              hipStream_t stream)
{
    const float* feat = (const float*)d_in[0];   // (N, 64) fp32
    const float* pts  = (const float*)d_in[1];   // (N, 3)  fp32
    float* out = (float*)d_out;                  // (64,64,64,64) fp32

    const int n = in_sizes[0] / NCH;

    // Workspace (ints): rec (NCELLS*16) | nspill (1,+3 pad) | spill (2*SPILLCAP)
    // Total: 4194304 + 4 + 16384 ints = ~16.8 MB.
    int* rec    = (int*)d_ws;                    // NCELLS * 16, 64-B records
    int* nspill = rec + (size_t)NCELLS * 16;     // 1 (+3 pad)
    int* spill  = nspill + 4;                    // 2*SPILLCAP

    (void)hipMemsetAsync(rec, 0, ((size_t)NCELLS * 16 + 4) * sizeof(int), stream);

    int t8 = (n + 7) / 8;
    int pblocks = (t8 + 255) / 256;
    assign_pts<<<pblocks, 256, 0, stream>>>(pts, rec, nspill, spill, n);

    // 65536 waves (4 cells each) = 16384 blocks of 4 waves.
    reduce_bucket<<<NCELLS / 16, 256, 0, stream>>>(
        (const float4*)feat, rec, nspill, spill, (float4*)out);
}